// Round 10
// baseline (156.877 us; speedup 1.0000x reference)
//
#include <hip/hip_runtime.h>
#include <cstdint>
#include <cstddef>

#define KCAT  384
#define GNPB  8       // nodes per gather block = 1 node per wave
#define EROWS 28      // edges staged in LDS per node (7 async16); tail 29..32 via regs
#define MROWS 64      // rows per gemm block
#define AST   264     // gemm LDS A row stride elems (528B): 2-way banks on frag reads
#define VP_BLOCKS 24

typedef __attribute__((ext_vector_type(8))) short bf16x8;
typedef __attribute__((ext_vector_type(4))) float f32x4;

static __device__ __forceinline__ unsigned short f2bf(float f) {
    unsigned int u = __builtin_bit_cast(unsigned int, f);
    u += 0x7fffu + ((u >> 16) & 1u);
    return (unsigned short)(u >> 16);
}
static __device__ __forceinline__ float bfhi(unsigned int u) { return __builtin_bit_cast(float, u & 0xFFFF0000u); }
static __device__ __forceinline__ float bflo(unsigned int u) { return __builtin_bit_cast(float, u << 16); }
// masked bf16x8 accumulate (m=~0 keep, 0 drop; bf16 0x0000 == +0.0)
static __device__ __forceinline__ void acc8(float* a, const uint4& v, unsigned m) {
    unsigned x0 = v.x & m, x1 = v.y & m, x2 = v.z & m, x3 = v.w & m;
    a[0] += bflo(x0); a[1] += bfhi(x0); a[2] += bflo(x1); a[3] += bfhi(x1);
    a[4] += bflo(x2); a[5] += bfhi(x2); a[6] += bflo(x3); a[7] += bfhi(x3);
}
// async global->LDS, 16B/lane; LDS dest = wave-uniform base + lane*16; gptr per-lane
static __device__ __forceinline__ void async16(const unsigned short* g, void* lds_wave_base) {
    __builtin_amdgcn_global_load_lds(
        (const __attribute__((address_space(1))) void*)g,
        (__attribute__((address_space(3))) void*)lds_wave_base,
        16, 0, 0);
}

// ---------------- Prep: Vp pack (GEMM B layout), xb = bf16(x), blkoff ----------------
// Vp: element ((g*12 + s)*64 + lane)*8 + j = W[g*16 + (lane&15)][s*32 + (lane>>4)*8 + j]
__global__ __launch_bounds__(256)
void prep(const float* __restrict__ x, const float* __restrict__ Wg,
          const float* __restrict__ Wl, const float* __restrict__ Ws,
          const int* __restrict__ dst, unsigned short* __restrict__ Vp,
          unsigned short* __restrict__ xb, int* __restrict__ blkoff,
          int total8, int nblk_g, int noffb, int E) {
    const int bx = blockIdx.x, t = threadIdx.x;
    if (bx < VP_BLOCKS) {
        int gid = bx * 256 + t;
        if (gid < 6144) {
            int l = gid & 63, srow = (gid >> 6) % 12, g = gid / 768;
            int o = g * 16 + (l & 15);
            int k = srow * 32 + (l >> 4) * 8;
            const float* w; int kk;
            if (k < 128)      { w = Wg; kk = k; }
            else if (k < 256) { w = Wl; kk = k - 128; }
            else              { w = Ws; kk = k - 256; }
            const float* p = w + o * 128 + kk;
            uint4 u;
            u.x = (unsigned)f2bf(p[0]) | ((unsigned)f2bf(p[1]) << 16);
            u.y = (unsigned)f2bf(p[2]) | ((unsigned)f2bf(p[3]) << 16);
            u.z = (unsigned)f2bf(p[4]) | ((unsigned)f2bf(p[5]) << 16);
            u.w = (unsigned)f2bf(p[6]) | ((unsigned)f2bf(p[7]) << 16);
            ((uint4*)Vp)[gid] = u;
        }
    } else if (bx < VP_BLOCKS + noffb) {
        int b = (bx - VP_BLOCKS) * 256 + t;
        if (b < nblk_g) {
            int target = b * GNPB;
            int lo = 0, hi = E;
            while (lo < hi) { int mid = (lo + hi) >> 1; if (dst[mid] < target) lo = mid + 1; else hi = mid; }
            blkoff[b] = lo;
        }
    } else {
        int gid = (bx - VP_BLOCKS - noffb) * 256 + t;
        if (gid < total8) {
            const float4* px = (const float4*)x + (size_t)gid * 2;
            float4 a = px[0], bq = px[1];
            uint4 u;
            u.x = (unsigned)f2bf(a.x)  | ((unsigned)f2bf(a.y)  << 16);
            u.y = (unsigned)f2bf(a.z)  | ((unsigned)f2bf(a.w)  << 16);
            u.z = (unsigned)f2bf(bq.x) | ((unsigned)f2bf(bq.y) << 16);
            u.w = (unsigned)f2bf(bq.z) | ((unsigned)f2bf(bq.w) << 16);
            ((uint4*)xb)[gid] = u;
        }
    }
}

// ---------------- Gather: M[n] = (deg>0) ? mean_e xb[src[e]] : 0  (bf16) ----------------
// One node per WAVE, wave-PRIVATE async-LDS pipeline, NO barriers:
// issue 7 global_load_lds (28 scattered 256B rows) + <=1 reg tail row, then ONE
// wave-local `s_waitcnt vmcnt(0)` (inline asm, memory clobber), reduce from LDS.
// 8 waves x 7168B = 57344B LDS -> 2 blocks/CU = 16 waves/CU, ~7KB in flight each.
// NOTE: every __shfl sits under a WAVE-UNIFORM guard (d is per-wave) — shfl from
// EXEC-inactive lanes is undefined (R9 bug: per-lane tail guard broke deg 29..31).
__global__ __launch_bounds__(512)
void gather(const unsigned short* __restrict__ xb, const int* __restrict__ src,
            const int* __restrict__ deg, const int* __restrict__ blkoff,
            unsigned short* __restrict__ M, int N) {
    __shared__ __align__(16) unsigned short Ebuf[GNPB * 3584];   // 57344 B
    const int t = threadIdx.x, wv = t >> 6, lane = t & 63;
    const int c = lane & 15, p = lane >> 4;
    const int base = blockIdx.x * GNPB;

    // per-wave node start via redundant 8-wide scan (broadcast loads, no LDS)
    int dg = 0;
    if (lane < GNPB && base + lane < N) dg = deg[base + lane];
    int incl = dg;
#pragma unroll
    for (int off = 1; off < GNPB; off <<= 1) {
        int v = __shfl_up(incl, off, 64);
        if (lane >= off) incl += v;
    }
    const int d = __shfl(dg, wv, 64);
    const int s = blkoff[blockIdx.x] + __shfl(incl, wv, 64) - d;
    const int n = base + wv;
    const bool active = (n < N) && (d > 0);

    int sidx = 0;
    if (lane < d) sidx = src[s + lane];          // one coalesced shot, d <= 32

    char* eb = (char*)Ebuf + wv * 7168;
    if (active) {
#pragma unroll
        for (int i = 0; i < 7; ++i) {
            if (4 * i < d) {                     // wave-uniform guard
                int le = 4 * i + p;
                if (le > d - 1) le = d - 1;      // per-lane clamp (dups masked later)
                int ridx = __shfl(sidx, le, 64); // all lanes active here
                async16(xb + (size_t)ridx * 128 + c * 8, eb + i * 1024);
            }
        }
    }
    // register tail rows 28..31: WAVE-UNIFORM guard (d > EROWS); per-lane source
    // clamp keeps the shfl well-defined; dup loads masked in the accumulate.
    const int et = EROWS + p;
    uint4 vt = {0, 0, 0, 0};
    if (d > EROWS) {                             // wave-uniform -> all lanes at the shfl
        int etc = (et < d) ? et : d - 1;
        int ridx = __shfl(sidx, etc, 64);
        vt = *(const uint4*)(xb + (size_t)ridx * 128 + c * 8);
    }
    asm volatile("s_waitcnt vmcnt(0)" ::: "memory");   // wave-local drain, no barrier

    float a[8] = {0,0,0,0,0,0,0,0};
    float b2[8] = {0,0,0,0,0,0,0,0};
    if (active) {
#pragma unroll
        for (int g = 0; g < 7; ++g) {
            int e = 4 * g + p;
            uint4 v = *(const uint4*)(eb + e * 256 + c * 16);
            acc8((g & 1) ? b2 : a, v, (e < d) ? ~0u : 0u);
        }
        acc8(b2, vt, (et < d) ? ~0u : 0u);       // mask tail dups/overflow lanes
    }
#pragma unroll
    for (int i = 0; i < 8; ++i) a[i] += b2[i];
#pragma unroll
    for (int i = 0; i < 8; ++i) {
        a[i] += __shfl_xor(a[i], 16, 64);
        a[i] += __shfl_xor(a[i], 32, 64);
    }
    if (p == 0 && n < N) {
        float inv = (d > 0) ? 1.0f / (float)d : 0.0f;
        uint4 u;
        u.x = (unsigned)f2bf(a[0]*inv) | ((unsigned)f2bf(a[1]*inv) << 16);
        u.y = (unsigned)f2bf(a[2]*inv) | ((unsigned)f2bf(a[3]*inv) << 16);
        u.z = (unsigned)f2bf(a[4]*inv) | ((unsigned)f2bf(a[5]*inv) << 16);
        u.w = (unsigned)f2bf(a[6]*inv) | ((unsigned)f2bf(a[7]*inv) << 16);
        ((uint4*)M)[(size_t)n * 16 + c] = u;
    }
}

// ---------------- GEMM: out = elu([xb | M | mask.xb] @ V^T + b) ----------------
// 64 rows/block, 782 blocks, 256 threads, 33.8KB LDS -> 4 blocks/CU. A staged once
// (1 barrier). Each wave: 2 col-groups x 4 row-tiles x 12 ksteps = 96 MFMAs; B from
// packed Vp (1KB contiguous wave reads, L2-resident) w/ prefetch; mask.x K-segment
// synthesized by ANDing the x fragment with per-row deg masks.
__global__ __launch_bounds__(256)
void gemm(const unsigned short* __restrict__ xb, const unsigned short* __restrict__ Mm,
          const int* __restrict__ deg, const unsigned short* __restrict__ Vp,
          const float* __restrict__ bias, float* __restrict__ out, int N) {
    __shared__ __align__(16) unsigned short As[MROWS * AST];   // 33792 B
    __shared__ unsigned smask[MROWS];
    const int t = threadIdx.x, wv = t >> 6, lane = t & 63;
    const int c = lane & 15, quad = lane >> 4;
    const int base = blockIdx.x * MROWS;

    if (t < MROWS) smask[t] = (base + t < N && deg[base + t] > 0) ? 0xFFFFFFFFu : 0u;
#pragma unroll
    for (int it = 0; it < 8; ++it) {
        int f = it * 256 + t;
        int row = f >> 5, ch = f & 31;
        int grow = base + row; if (grow > N - 1) grow = N - 1;
        const unsigned short* gp = (ch < 16)
            ? xb + (size_t)grow * 128 + ch * 8
            : Mm + (size_t)grow * 128 + (ch - 16) * 8;
        *(uint4*)(As + row * AST + ch * 8) = *(const uint4*)gp;
    }
    __syncthreads();

    const int g0 = 2 * wv, g1 = 2 * wv + 1;
    const bf16x8* VB = (const bf16x8*)Vp;
    f32x4 acc[4][2];
#pragma unroll
    for (int r = 0; r < 4; ++r) { acc[r][0] = (f32x4){0,0,0,0}; acc[r][1] = (f32x4){0,0,0,0}; }

    bf16x8 b0 = VB[(g0 * 12) * 64 + lane];
    bf16x8 b1 = VB[(g1 * 12) * 64 + lane];
#pragma unroll
    for (int s = 0; s < 12; ++s) {
        int sn = (s + 1 < 12) ? s + 1 : 0;
        bf16x8 n0 = VB[(g0 * 12 + sn) * 64 + lane];
        bf16x8 n1 = VB[(g1 * 12 + sn) * 64 + lane];
        int seg = s >> 2, kk = (s & 3) * 32;
#pragma unroll
        for (int r = 0; r < 4; ++r) {
            bf16x8 afr = *(const bf16x8*)(As + (16 * r + c) * AST + (seg == 1 ? 128 : 0) + kk + quad * 8);
            if (seg == 2) {
                unsigned m = smask[16 * r + c];
                uint4 ai = __builtin_bit_cast(uint4, afr);
                ai.x &= m; ai.y &= m; ai.z &= m; ai.w &= m;
                afr = __builtin_bit_cast(bf16x8, ai);
            }
            acc[r][0] = __builtin_amdgcn_mfma_f32_16x16x32_bf16(afr, b0, acc[r][0], 0, 0, 0);
            acc[r][1] = __builtin_amdgcn_mfma_f32_16x16x32_bf16(afr, b1, acc[r][1], 0, 0, 0);
        }
        b0 = n0; b1 = n1;
    }

    // epilogue: + bias, ELU, store. C/D: col=lane&15, row=quad*4+reg
    const int col0 = g0 * 16 + c, col1 = g1 * 16 + c;
    const float bv0 = bias[col0], bv1 = bias[col1];
#pragma unroll
    for (int r = 0; r < 4; ++r) {
#pragma unroll
        for (int reg = 0; reg < 4; ++reg) {
            int grow = base + 16 * r + quad * 4 + reg;
            if (grow < N) {
                float v0 = acc[r][0][reg] + bv0;
                float v1 = acc[r][1][reg] + bv1;
                out[(size_t)grow * 128 + col0] = (v0 > 0.f) ? v0 : __expf(v0) - 1.0f;
                out[(size_t)grow * 128 + col1] = (v1 > 0.f) ? v1 : __expf(v1) - 1.0f;
            }
        }
    }
}

extern "C" void kernel_launch(void* const* d_in, const int* in_sizes, int n_in,
                              void* d_out, int out_size, void* d_ws, size_t ws_size,
                              hipStream_t stream) {
    const float* x  = (const float*)d_in[0];
    const float* Wg = (const float*)d_in[1];
    const float* Wl = (const float*)d_in[2];
    const float* Ws = (const float*)d_in[3];
    const float* b  = (const float*)d_in[4];
    const int*   src = (const int*)d_in[5];
    const int*   dst = (const int*)d_in[6];
    const int*   deg = (const int*)d_in[7];
    const int E = in_sizes[5];
    const int N = in_sizes[7];
    float* out = (float*)d_out;

    const size_t NB = (size_t)N * 128 * 2;                       // 12.8 MB
    unsigned short* Vp     = (unsigned short*)d_ws;              // 96 KB packed B
    int*            blkoff = (int*)((char*)d_ws + 98304);        // 32 KB reserved
    unsigned short* xb     = (unsigned short*)((char*)d_ws + 131072);
    unsigned short* Mm     = (unsigned short*)((char*)d_ws + 131072 + NB);

    const int nblk_g = (N + GNPB - 1) / GNPB;      // 6250
    const int noffb  = (nblk_g + 255) / 256;       // 25
    const int total8 = N * 16;
    const int nconv  = (total8 + 255) / 256;       // 3125

    prep<<<dim3(VP_BLOCKS + noffb + nconv), dim3(256), 0, stream>>>(
        x, Wg, Wl, Ws, dst, Vp, xb, blkoff, total8, nblk_g, noffb, E);
    gather<<<dim3(nblk_g), dim3(512), 0, stream>>>(xb, src, deg, blkoff, Mm, N);
    gemm<<<dim3((N + MROWS - 1) / MROWS), dim3(256), 0, stream>>>(xb, Mm, deg, Vp, b, out, N);
}

// Round 11
// 149.742 us; speedup vs baseline: 1.0476x; 1.0476x over previous
//
#include <hip/hip_runtime.h>
#include <cstdint>
#include <cstddef>

#define KCAT 384
#define GNPB 8        // nodes per gather block (8 waves, 1 node/wave)
#define MNPB 16       // rows per gemm block
#define GAST 264      // gemm LDS A row stride in elems (528 B)
#define VP_BLOCKS 24  // prep blocks packing Vp

typedef __attribute__((ext_vector_type(8))) short bf16x8;
typedef __attribute__((ext_vector_type(4))) float f32x4;

static __device__ __forceinline__ unsigned short f2bf(float f) {
    unsigned int u = __builtin_bit_cast(unsigned int, f);
    u += 0x7fffu + ((u >> 16) & 1u);
    return (unsigned short)(u >> 16);
}
// fp8 e4m3 x4 (one uint) -> accumulate 4 f32 with AND-mask (fp8 0x00 == +0.0)
static __device__ __forceinline__ void accf8x4(float* a, unsigned w, unsigned m) {
    w &= m;
    a[0] += __builtin_amdgcn_cvt_f32_fp8(w, 0);
    a[1] += __builtin_amdgcn_cvt_f32_fp8(w, 1);
    a[2] += __builtin_amdgcn_cvt_f32_fp8(w, 2);
    a[3] += __builtin_amdgcn_cvt_f32_fp8(w, 3);
}

// ---------------- Prep: Vp pack (GEMM B layout), xb = bf16(x), x8 = fp8(x), blkoff ----------------
// Vp: element ((g*12 + s)*64 + lane)*8 + j = W[g*16 + (lane&15)][s*32 + (lane>>4)*8 + j]
__global__ __launch_bounds__(256)
void prep(const float* __restrict__ x, const float* __restrict__ Wg,
          const float* __restrict__ Wl, const float* __restrict__ Ws,
          const int* __restrict__ dst, unsigned short* __restrict__ Vp,
          unsigned short* __restrict__ xb, unsigned* __restrict__ x8,
          int* __restrict__ blkoff, int total8, int nblk_g, int noffb, int E) {
    const int bx = blockIdx.x, t = threadIdx.x;
    if (bx < VP_BLOCKS) {
        int gid = bx * 256 + t;
        if (gid < 6144) {
            int l = gid & 63, srow = (gid >> 6) % 12, g = gid / 768;
            int o = g * 16 + (l & 15);
            int k = srow * 32 + (l >> 4) * 8;
            const float* w; int kk;
            if (k < 128)      { w = Wg; kk = k; }
            else if (k < 256) { w = Wl; kk = k - 128; }
            else              { w = Ws; kk = k - 256; }
            const float* p = w + o * 128 + kk;
            uint4 u;
            u.x = (unsigned)f2bf(p[0]) | ((unsigned)f2bf(p[1]) << 16);
            u.y = (unsigned)f2bf(p[2]) | ((unsigned)f2bf(p[3]) << 16);
            u.z = (unsigned)f2bf(p[4]) | ((unsigned)f2bf(p[5]) << 16);
            u.w = (unsigned)f2bf(p[6]) | ((unsigned)f2bf(p[7]) << 16);
            ((uint4*)Vp)[gid] = u;
        }
    } else if (bx < VP_BLOCKS + noffb) {
        int b = (bx - VP_BLOCKS) * 256 + t;
        if (b < nblk_g) {
            int target = b * GNPB;
            int lo = 0, hi = E;
            while (lo < hi) { int mid = (lo + hi) >> 1; if (dst[mid] < target) lo = mid + 1; else hi = mid; }
            blkoff[b] = lo;
        }
    } else {
        int gid = (bx - VP_BLOCKS - noffb) * 256 + t;
        if (gid < total8) {
            const float4* px = (const float4*)x + (size_t)gid * 2;
            float4 a = px[0], bq = px[1];
            uint4 u;
            u.x = (unsigned)f2bf(a.x)  | ((unsigned)f2bf(a.y)  << 16);
            u.y = (unsigned)f2bf(a.z)  | ((unsigned)f2bf(a.w)  << 16);
            u.z = (unsigned)f2bf(bq.x) | ((unsigned)f2bf(bq.y) << 16);
            u.w = (unsigned)f2bf(bq.z) | ((unsigned)f2bf(bq.w) << 16);
            ((uint4*)xb)[gid] = u;
            // fp8 e4m3 pack: byte k of word = feature k (little-endian)
            int w0 = __builtin_amdgcn_cvt_pk_fp8_f32(a.x,  a.y,  0,  false);
            w0     = __builtin_amdgcn_cvt_pk_fp8_f32(a.z,  a.w,  w0, true);
            int w1 = __builtin_amdgcn_cvt_pk_fp8_f32(bq.x, bq.y, 0,  false);
            w1     = __builtin_amdgcn_cvt_pk_fp8_f32(bq.z, bq.w, w1, true);
            uint2 p8; p8.x = (unsigned)w0; p8.y = (unsigned)w1;
            ((uint2*)x8)[gid] = p8;
        }
    }
}

// ---------------- Gather: M[n] = (deg>0) ? mean_e fp8(x)[src[e]] : 0  (bf16 out) ----------------
// One node per wave, 8 waves/block, barrier-free, LDS-free. Row = 128B fp8.
// lane = parity(p=lane>>3, 8 parities) x 16B-col(c=lane&7, 16 feats each).
// ALL <=32 edge rows issued in one batch (4 uint4/lane); wave-uniform round guards
// cap clamp-waste at <8 rows/node. Every __shfl under wave-uniform control flow.
__global__ __launch_bounds__(512, 7)
void gather(const unsigned* __restrict__ x8, const int* __restrict__ src,
            const int* __restrict__ deg, const int* __restrict__ blkoff,
            unsigned short* __restrict__ M, int N) {
    const int t = threadIdx.x, wv = t >> 6, lane = t & 63;
    const int c = lane & 7, p = lane >> 3;
    const int base = blockIdx.x * GNPB;

    // redundant 8-wide deg scan (broadcast loads, no LDS/barrier)
    int dg = 0;
    if (lane < GNPB && base + lane < N) dg = deg[base + lane];
    int incl = dg;
#pragma unroll
    for (int off = 1; off < GNPB; off <<= 1) {
        int v = __shfl_up(incl, off, 64);
        if (lane >= off) incl += v;
    }
    const int d = __shfl(dg, wv, 64);
    const int s = blkoff[blockIdx.x] + __shfl(incl, wv, 64) - d;
    const int n = base + wv;

    int sidx = 0;
    if (lane < d) sidx = src[s + lane];          // one coalesced shot, d <= 32

    const uint4* X = (const uint4*)x8;           // row = 8 uint4 (128 fp8)
    float acc[16] = {0,0,0,0,0,0,0,0,0,0,0,0,0,0,0,0};
    if (n < N && d > 0) {                        // wave-uniform
        uint4 v[4]; unsigned mk[4];
        const int ng = (d + 7) >> 3;             // 1..4 rounds, wave-uniform
#pragma unroll
        for (int g = 0; g < 4; ++g) {
            if (g < ng) {                        // wave-uniform guard
                int e  = g * 8 + p;
                int le = (e < d) ? e : d - 1;    // per-lane clamp (dups masked)
                int r  = __shfl(sidx, le, 64);   // all lanes active
                v[g]  = X[(size_t)r * 8 + c];
                mk[g] = (e < d) ? ~0u : 0u;
            } else { v[g] = (uint4){0,0,0,0}; mk[g] = 0u; }
        }
#pragma unroll
        for (int g = 0; g < 4; ++g) {
            accf8x4(acc,      v[g].x, mk[g]);
            accf8x4(acc + 4,  v[g].y, mk[g]);
            accf8x4(acc + 8,  v[g].z, mk[g]);
            accf8x4(acc + 12, v[g].w, mk[g]);
        }
    }
    // reduce across the 8 parities (lanes c, c+8, ..., c+56)
#pragma unroll
    for (int i = 0; i < 16; ++i) {
        acc[i] += __shfl_xor(acc[i], 8, 64);
        acc[i] += __shfl_xor(acc[i], 16, 64);
        acc[i] += __shfl_xor(acc[i], 32, 64);
    }
    if (p == 0 && n < N) {
        float inv = (d > 0) ? 1.0f / (float)d : 0.0f;
        uint4 u0, u1;
        u0.x = (unsigned)f2bf(acc[0]*inv)  | ((unsigned)f2bf(acc[1]*inv)  << 16);
        u0.y = (unsigned)f2bf(acc[2]*inv)  | ((unsigned)f2bf(acc[3]*inv)  << 16);
        u0.z = (unsigned)f2bf(acc[4]*inv)  | ((unsigned)f2bf(acc[5]*inv)  << 16);
        u0.w = (unsigned)f2bf(acc[6]*inv)  | ((unsigned)f2bf(acc[7]*inv)  << 16);
        u1.x = (unsigned)f2bf(acc[8]*inv)  | ((unsigned)f2bf(acc[9]*inv)  << 16);
        u1.y = (unsigned)f2bf(acc[10]*inv) | ((unsigned)f2bf(acc[11]*inv) << 16);
        u1.z = (unsigned)f2bf(acc[12]*inv) | ((unsigned)f2bf(acc[13]*inv) << 16);
        u1.w = (unsigned)f2bf(acc[14]*inv) | ((unsigned)f2bf(acc[15]*inv) << 16);
        ((uint4*)M)[(size_t)n * 16 + c * 2]     = u0;
        ((uint4*)M)[(size_t)n * 16 + c * 2 + 1] = u1;
    }
}

// ---------------- GEMM: out = elu([xb | M | mask.xb] @ V^T + b) ----------------
// 16 rows/block, 3125 blocks, 256 threads. A-panel staged once -> single barrier.
// Third K-segment = xb LDS data ANDed with per-row deg mask. B streamed from packed
// Vp (contiguous 1KB wave reads, L2-resident) with register prefetch; no K-loop barriers.
__global__ __launch_bounds__(256)
void gemm(const unsigned short* __restrict__ xb, const unsigned short* __restrict__ Mm,
          const int* __restrict__ deg, const unsigned short* __restrict__ Vp,
          const float* __restrict__ bias, float* __restrict__ out, int N) {
    __shared__ __align__(16) unsigned short As[MNPB * GAST];
    __shared__ unsigned smask[MNPB];
    const int t = threadIdx.x, wv = t >> 6, lane = t & 63;
    const int c = lane & 15, quad = lane >> 4;
    const int base = blockIdx.x * MNPB;

    if (t < MNPB) smask[t] = (base + t < N && deg[base + t] > 0) ? 0xFFFFFFFFu : 0u;
#pragma unroll
    for (int it = 0; it < 2; ++it) {
        int f = it * 256 + t;
        int row = f >> 5, ch = f & 31;
        int grow = base + row; if (grow > N - 1) grow = N - 1;
        const unsigned short* gp = (ch < 16)
            ? xb + (size_t)grow * 128 + ch * 8
            : Mm + (size_t)grow * 128 + (ch - 16) * 8;
        *(uint4*)(As + row * GAST + ch * 8) = *(const uint4*)gp;
    }
    __syncthreads();

    const unsigned msk = smask[c];
    const int g0 = 2 * wv, g1 = 2 * wv + 1;
    const bf16x8* VB = (const bf16x8*)Vp;

    f32x4 acc0 = (f32x4){0.f, 0.f, 0.f, 0.f};
    f32x4 acc1 = (f32x4){0.f, 0.f, 0.f, 0.f};
    bf16x8 b0 = VB[(g0 * 12) * 64 + lane];
    bf16x8 b1 = VB[(g1 * 12) * 64 + lane];
#pragma unroll
    for (int s2 = 0; s2 < 12; ++s2) {
        int sn = (s2 + 1 < 12) ? s2 + 1 : 0;        // branchless prefetch
        bf16x8 n0 = VB[(g0 * 12 + sn) * 64 + lane];
        bf16x8 n1 = VB[(g1 * 12 + sn) * 64 + lane];
        int seg = s2 >> 2, kk = (s2 & 3) * 32;
        bf16x8 a0 = *(const bf16x8*)(As + c * GAST + (seg == 1 ? 128 : 0) + kk + quad * 8);
        if (seg == 2) {                              // mask.x segment
            uint4 ai = __builtin_bit_cast(uint4, a0);
            ai.x &= msk; ai.y &= msk; ai.z &= msk; ai.w &= msk;
            a0 = __builtin_bit_cast(bf16x8, ai);
        }
        acc0 = __builtin_amdgcn_mfma_f32_16x16x32_bf16(a0, b0, acc0, 0, 0, 0);
        acc1 = __builtin_amdgcn_mfma_f32_16x16x32_bf16(a0, b1, acc1, 0, 0, 0);
        b0 = n0; b1 = n1;
    }

    // epilogue: + bias, ELU, store. C/D: col=lane&15, row=quad*4+reg
    const int col0 = g0 * 16 + c, col1 = g1 * 16 + c;
    const float bv0 = bias[col0], bv1 = bias[col1];
#pragma unroll
    for (int reg = 0; reg < 4; ++reg) {
        int grow = base + quad * 4 + reg;
        if (grow < N) {
            float v0 = acc0[reg] + bv0;
            float v1 = acc1[reg] + bv1;
            out[(size_t)grow * 128 + col0] = (v0 > 0.f) ? v0 : __expf(v0) - 1.0f;
            out[(size_t)grow * 128 + col1] = (v1 > 0.f) ? v1 : __expf(v1) - 1.0f;
        }
    }
}

extern "C" void kernel_launch(void* const* d_in, const int* in_sizes, int n_in,
                              void* d_out, int out_size, void* d_ws, size_t ws_size,
                              hipStream_t stream) {
    const float* x  = (const float*)d_in[0];
    const float* Wg = (const float*)d_in[1];
    const float* Wl = (const float*)d_in[2];
    const float* Ws = (const float*)d_in[3];
    const float* b  = (const float*)d_in[4];
    const int*   src = (const int*)d_in[5];
    const int*   dst = (const int*)d_in[6];
    const int*   deg = (const int*)d_in[7];
    const int E = in_sizes[5];
    const int N = in_sizes[7];
    float* out = (float*)d_out;

    const size_t NB = (size_t)N * 128 * 2;                       // 12.8 MB
    unsigned short* Vp     = (unsigned short*)d_ws;              // 96 KB packed B
    int*            blkoff = (int*)((char*)d_ws + 98304);        // 32 KB reserved
    unsigned short* xb     = (unsigned short*)((char*)d_ws + 131072);
    unsigned short* Mm     = (unsigned short*)((char*)d_ws + 131072 + NB);
    unsigned*       x8     = (unsigned*)((char*)d_ws + 131072 + 2 * NB);   // 6.4 MB

    const int nblk_g = (N + GNPB - 1) / GNPB;      // 6250
    const int noffb  = (nblk_g + 255) / 256;       // 25
    const int total8 = N * 16;
    const int nconv  = (total8 + 255) / 256;       // 3125

    prep<<<dim3(VP_BLOCKS + noffb + nconv), dim3(256), 0, stream>>>(
        x, Wg, Wl, Ws, dst, Vp, xb, x8, blkoff, total8, nblk_g, noffb, E);
    gather<<<dim3(nblk_g), dim3(512), 0, stream>>>(x8, src, deg, blkoff, Mm, N);
    gemm<<<dim3((N + MNPB - 1) / MNPB), dim3(256), 0, stream>>>(xb, Mm, deg, Vp, b, out, N);
}